// Round 24
// baseline (527.653 us; speedup 1.0000x reference)
//
#include <hip/hip_runtime.h>
#include <hip/hip_bf16.h>
#include <math.h>

typedef unsigned int uint;
typedef unsigned short ushort;
typedef __attribute__((ext_vector_type(8))) short short8;
typedef __attribute__((ext_vector_type(4))) float f32x4;
typedef __attribute__((ext_vector_type(16))) float f32x16;
typedef __attribute__((ext_vector_type(4))) uint uint4v;

#define SCALE_Q 0.18257418583505536f   // 30^-0.5  (baked into Wq/bq)
#define LOG2E 1.4426950408889634f      // baked into Wk and bias_s

__device__ __forceinline__ ushort f2bf(float f) {
    union { float f; uint i; } v; v.f = f;
    uint i = v.i;
    uint r = (i + 0x7fffu + ((i >> 16) & 1u)) >> 16;
    return (ushort)r;
}
__device__ __forceinline__ float bf2f(ushort u) {
    union { uint i; float f; } v; v.i = ((uint)u) << 16; return v.f;
}

// ---------------------------------------------------------------------------
// Prep (weights + attention bias in ONE kernel).
// Softmax scales folded into the QKV weights: Q cols x SCALE_Q, K cols x LOG2E.
// bias_s[h][key/4][q][4] f32 = rpb[rpi[q*576+key]*6+h] * LOG2E
// ---------------------------------------------------------------------------
__global__ void prep_kernel(const float* __restrict__ qkv_w, const float* __restrict__ qkv_b,
                            const float* __restrict__ proj_w, const float* __restrict__ proj_b,
                            const float* __restrict__ w1, const float* __restrict__ b1,
                            const float* __restrict__ w2, const float* __restrict__ b2,
                            const int* __restrict__ rpi, const float* __restrict__ rpb,
                            ushort* __restrict__ wq_t, ushort* __restrict__ wp_t,
                            ushort* __restrict__ w1_t, ushort* __restrict__ w2_t,
                            float* __restrict__ bq, float* __restrict__ bp,
                            float* __restrict__ b1p, float* __restrict__ b2p,
                            float* __restrict__ bias_s)
{
    int i = blockIdx.x * 256 + threadIdx.x;
    if (i < 576 * 192) { int n = i / 192, k = i % 192;
        float sc = (n < 180) ? SCALE_Q : ((n < 360) ? LOG2E : 1.f);
        wq_t[i] = (n < 540 && k < 180) ? f2bf(qkv_w[k * 540 + n] * sc) : (ushort)0; return; }
    i -= 576 * 192;
    if (i < 192 * 192) { int n = i / 192, k = i % 192;
        int h = k >> 5, d = k & 31;
        wp_t[i] = (n < 180 && d < 30) ? f2bf(proj_w[(h * 30 + d) * 180 + n]) : (ushort)0; return; }
    i -= 192 * 192;
    if (i < 384 * 192) { int n = i / 192, k = i % 192;
        w1_t[i] = (n < 360 && k < 180) ? f2bf(w1[k * 360 + n]) : (ushort)0; return; }
    i -= 384 * 192;
    if (i < 192 * 384) { int n = i / 384, k = i % 384;
        w2_t[i] = (n < 180 && k < 360) ? f2bf(w2[k * 180 + n]) : (ushort)0; return; }
    i -= 192 * 384;
    if (i < 576) {
        float sc = (i < 180) ? SCALE_Q : ((i < 360) ? LOG2E : 1.f);
        bq[i] = (i < 540) ? qkv_b[i] * sc : 0.f; return; }
    i -= 576;
    if (i < 192) { bp[i] = (i < 180) ? proj_b[i] : 0.f; return; }
    i -= 192;
    if (i < 384) { b1p[i] = (i < 360) ? b1[i] : 0.f; return; }
    i -= 384;
    if (i < 192) { b2p[i] = (i < 180) ? b2[i] : 0.f; return; }
    i -= 192;
    if (i < 221184) {   // bias part
        int h = i / 36864;
        int r = i % 36864;                         // kg*256 + q
        int kg = r >> 8, q = r & 255;
        const int* rp = rpi + q * 576 + kg * 4;
        f32x4 v;
        #pragma unroll
        for (int j = 0; j < 4; ++j) v[j] = rpb[rp[j] * 6 + h] * LOG2E;
        *(f32x4*)(bias_s + (long)i * 4) = v;
    }
}

// ---------------------------------------------------------------------------
// LayerNorm: [rows][180] (f32 or bf16 input) -> bf16 [rows][192]; pads ZEROED
// ---------------------------------------------------------------------------
template<int IN_BF16>
__global__ void ln_kernel(const void* __restrict__ xin, const float* __restrict__ g,
                          const float* __restrict__ b, ushort* __restrict__ out)
{
    int row = blockIdx.x * 4 + (threadIdx.x >> 6);
    int lane = threadIdx.x & 63;
    float v0, v1, v2;
    if (IN_BF16) {
        const ushort* xr = (const ushort*)xin + (long)row * 180;
        v0 = bf2f(xr[lane]);
        v1 = bf2f(xr[lane + 64]);
        v2 = (lane < 52) ? bf2f(xr[lane + 128]) : 0.f;
    } else {
        const float* xr = (const float*)xin + (long)row * 180;
        v0 = xr[lane];
        v1 = xr[lane + 64];
        v2 = (lane < 52) ? xr[lane + 128] : 0.f;
    }
    float s = v0 + v1 + v2;
    float ss = v0 * v0 + v1 * v1 + v2 * v2;
    #pragma unroll
    for (int m = 1; m < 64; m <<= 1) { s += __shfl_xor(s, m); ss += __shfl_xor(ss, m); }
    float mu = s * (1.f / 180.f);
    float var = ss * (1.f / 180.f) - mu * mu;
    float rs = rsqrtf(var + 1e-5f);
    ushort* orow = out + (long)row * 192;
    orow[lane]      = f2bf((v0 - mu) * rs * g[lane] + b[lane]);
    orow[lane + 64] = f2bf((v1 - mu) * rs * g[lane + 64] + b[lane + 64]);
    orow[lane + 128] = (lane < 52)
        ? f2bf((v2 - mu) * rs * g[lane + 128] + b[lane + 128])
        : (ushort)0;
}

// ---------------------------------------------------------------------------
// GEMM, 128x128 tile, 2-phase dbuf, one barrier per k-step.
// XCD-chunked block swizzle (T1). R21-verified, byte-identical.
// EPI 0: bf16 = acc+bias, padded qkv layout, col<576 (540..575 -> pad slots)
// EPI 1: bf16 = acc+bias+aux_f32, stride 180, col<180      (proj + residual)
// EPI 2: bf16 = gelu(acc+bias), stride 384                 (mlp1)
// EPI 3: f32  = acc+bias+aux_bf16, stride 180, col<180     (mlp2 + residual)
// ---------------------------------------------------------------------------
template<int KP, int NBX, int EPI>
__global__ __launch_bounds__(256)
void gemm_kernel(const ushort* __restrict__ A, const ushort* __restrict__ Bt,
                 const float* __restrict__ bias, void* __restrict__ outp,
                 const void* __restrict__ aux)
{
    __shared__ ushort As[2][128 * 32];
    __shared__ ushort Bs[2][128 * 32];
    constexpr int TOTAL = NBX * 1024;
    const int lin = blockIdx.y * NBX + blockIdx.x;
    const int lin2 = (lin & 7) * (TOTAL >> 3) + (lin >> 3);
    const int m0 = (lin2 / NBX) * 128;
    const int n0 = (lin2 % NBX) * 128;
    const int tid = threadIdx.x;
    const int lane = tid & 63;
    const int w = tid >> 6;
    const int wr = w >> 1, wc = w & 1;
    const int lg = lane >> 4, lc = lane & 15;

    f32x4 acc[4][4] = {};

    const int arow = tid >> 2;
    const int acol = (tid & 3) * 8;
    const ushort* gA = A + (long)(m0 + arow) * KP + acol;
    const ushort* gB = Bt + (long)(n0 + arow) * KP + acol;

    typedef const __attribute__((address_space(1))) char* gp_t;
    typedef __attribute__((address_space(3))) char* lp_t;

    const int kg = lg * 8;
    const int rA = wr * 64 + lc;
    const int rB = wc * 64 + lc;

    #define STAGE(buf, k0)                                                          \
        do {                                                                        \
            __builtin_amdgcn_global_load_lds((gp_t)(const char*)(gA + (k0)),        \
                (lp_t)(char*)(As[buf] + tid * 8), 16, 0, 0);                        \
            __builtin_amdgcn_global_load_lds((gp_t)(const char*)(gA + 64 * KP + (k0)),\
                (lp_t)(char*)(As[buf] + 2048 + tid * 8), 16, 0, 0);                 \
            __builtin_amdgcn_global_load_lds((gp_t)(const char*)(gB + (k0)),        \
                (lp_t)(char*)(Bs[buf] + tid * 8), 16, 0, 0);                        \
            __builtin_amdgcn_global_load_lds((gp_t)(const char*)(gB + 64 * KP + (k0)),\
                (lp_t)(char*)(Bs[buf] + 2048 + tid * 8), 16, 0, 0);                 \
        } while (0)

    STAGE(0, 0);
    __syncthreads();
    int cur = 0;
    for (int k0 = 0; k0 < KP; k0 += 32) {
        if (k0 + 32 < KP) STAGE(cur ^ 1, k0 + 32);
        short8 a[4], bb[4];
        #pragma unroll
        for (int mi = 0; mi < 4; ++mi)
            a[mi] = *(const short8*)&As[cur][(rA + mi * 16) * 32 + kg];
        #pragma unroll
        for (int ni = 0; ni < 4; ++ni)
            bb[ni] = *(const short8*)&Bs[cur][(rB + ni * 16) * 32 + kg];
        #pragma unroll
        for (int mi = 0; mi < 4; ++mi)
            #pragma unroll
            for (int ni = 0; ni < 4; ++ni)
                acc[mi][ni] = __builtin_amdgcn_mfma_f32_16x16x32_bf16(
                    a[mi], bb[ni], acc[mi][ni], 0, 0, 0);
        __syncthreads();
        cur ^= 1;
    }
    #undef STAGE

    #pragma unroll
    for (int mi = 0; mi < 4; ++mi) {
        #pragma unroll
        for (int ni = 0; ni < 4; ++ni) {
            int col = n0 + wc * 64 + ni * 16 + lc;
            int rbase = m0 + wr * 64 + mi * 16 + lg * 4;
            float bcol = bias[col];
            if (EPI == 0) {
                if (col < 576) {
                    int seg, hh, dd;
                    if (col < 540) {
                        seg = col / 180; int r2 = col - seg * 180;
                        hh = r2 / 30; dd = r2 - hh * 30;
                    } else {
                        int s2 = col - 540;
                        seg = s2 / 12; int r3 = s2 - seg * 12;
                        hh = r3 >> 1; dd = 30 + (r3 & 1);
                    }
                    int slot = seg * 192 + hh * 32 + dd;
                    #pragma unroll
                    for (int r = 0; r < 4; ++r) {
                        long row = rbase + r;
                        ((ushort*)outp)[row * 576 + slot] = f2bf(acc[mi][ni][r] + bcol);
                    }
                }
            } else if (EPI == 1) {
                if (col < 180) {
                    #pragma unroll
                    for (int r = 0; r < 4; ++r) {
                        long row = rbase + r;
                        ((ushort*)outp)[row * 180 + col] =
                            f2bf(acc[mi][ni][r] + bcol + ((const float*)aux)[row * 180 + col]);
                    }
                }
            } else if (EPI == 2) {
                #pragma unroll
                for (int r = 0; r < 4; ++r) {
                    long row = rbase + r;
                    float v = acc[mi][ni][r] + bcol;
                    float t = 0.5f * v * (1.f + erff(v * 0.70710678118654752f));
                    ((ushort*)outp)[row * 384 + col] = f2bf(t);
                }
            } else {
                if (col < 180) {
                    #pragma unroll
                    for (int r = 0; r < 4; ++r) {
                        long row = rbase + r;
                        ((float*)outp)[row * 180 + col] =
                            acc[mi][ni][r] + bcol
                            + bf2f(((const ushort*)aux)[row * 180 + col]);
                    }
                }
            }
        }
    }
}

// ---------------------------------------------------------------------------
// MFMA attention (R22-verified): 8 waves/block (512 threads), wave owns 32 q
// rows; K/V staged once (t<256 stages K, t>=256 stages V); 32x32 MFMA,
// in-register P, 1 barrier/chunk.
// ---------------------------------------------------------------------------
__global__ __launch_bounds__(512)
void attn_kernel(const ushort* __restrict__ qkv, const float* __restrict__ bias_s,
                 ushort* __restrict__ obuf)
{
    __shared__ ushort K_lds[2][64 * 40];
    __shared__ ushort Vt_lds[2][32 * 64];

    const int blk0 = blockIdx.x;
    const int blk = (blk0 & 7) * 384 + (blk0 >> 3);   // XCD-contiguous swizzle
    const int head = blk % 6;
    const int win = blk / 6;
    const int wj = win & 15, wi = (win >> 4) & 15, b = win >> 8;
    const int t = threadIdx.x;
    const int lane = t & 63;
    const int w = t >> 6;           // 0..7: wave owns q-tile w*32..w*32+31
    const int l5 = lane >> 5;       // 0..1
    const int lc5 = lane & 31;      // 0..31

    // Q fragment: B-operand, col(n)=q by lc5, k=d, two d-slices of 16
    short8 qf[2];
    {
        int tok = w * 32 + lc5;
        int y = wi * 16 + (tok >> 4), x = wj * 16 + (tok & 15);
        long grow = (long)(b * 256 + y) * 256 + x;
        #pragma unroll
        for (int ksl = 0; ksl < 2; ++ksl)
            qf[ksl] = *(const short8*)(qkv + grow * 576 + head * 32 + ksl * 16 + l5 * 8);
    }

    f32x16 oacc = {};
    const short8 zv = {0, 0, 0, 0, 0, 0, 0, 0};

    // staging split: t<256 stage K, t>=256 stage V (same keyloc/p4 mapping)
    const int isK = (t < 256);
    const int st = t & 255;
    const int keyloc = st >> 2;   // chunk-local key staged by this thread
    const int p4 = st & 3;        // 16B d-block

    const f32x4* pch = (const f32x4*)bias_s
                       + ((long)(head * 144 + l5) << 8) + (w * 32 + lc5);

    const ushort* kvbase = qkv + head * 32 + p4 * 8 + (isK ? 192 : 384);

    short8 kv;
    int kyS = keyloc / 24, kxS = keyloc - (keyloc / 24) * 24;

    #define LOADKV()                                                           \
        do {                                                                   \
            int gy = wi * 16 - 4 + kyS, gx = wj * 16 - 4 + kxS;                \
            bool ok = (gy >= 0 && gy < 256 && gx >= 0 && gx < 256);            \
            long grow = ok ? ((long)(b * 256 + gy) * 256 + gx) : 0;            \
            kv = *(const short8*)(kvbase + grow * 576);                        \
            if (!ok) kv = zv;                                                  \
            kxS += 16; kyS += 2;                                               \
            if (kxS >= 24) { kxS -= 24; kyS += 1; }                            \
        } while (0)

    #define STORELDS(buf)                                                      \
        do {                                                                   \
            if (isK) {                                                         \
                *(short8*)&K_lds[buf][keyloc * 40 + p4 * 8] = kv;              \
            } else {                                                           \
                _Pragma("unroll")                                              \
                for (int j = 0; j < 8; ++j) {                                  \
                    int d = p4 * 8 + j;                                        \
                    int swd = (((d & 7) ^ (d >> 3)) << 3);                     \
                    Vt_lds[buf][d * 64 + (keyloc ^ swd)] = ((const ushort*)&kv)[j];\
                }                                                              \
                if (p4 == 3) Vt_lds[buf][31 * 64 + (keyloc ^ 32)] = (ushort)0x3F80;\
            }                                                                  \
        } while (0)

    LOADKV();
    STORELDS(0);
    LOADKV();

    const int vswd = (((lc5 & 7) ^ (lc5 >> 3)) << 3);

    for (int ch = 0; ch < 9; ++ch) {
        __syncthreads();
        const int buf = ch & 1;

        // V B-fragments for the 4 k-slices
        short8 vb[4];
        #pragma unroll
        for (int ksl = 0; ksl < 4; ++ksl)
            vb[ksl] = *(const short8*)&Vt_lds[buf][lc5 * 64 + ((ksl * 16 + l5 * 8) ^ vswd)];

        // K A-fragments
        short8 ka[2][2];
        #pragma unroll
        for (int ni = 0; ni < 2; ++ni) {
            ka[ni][0] = *(const short8*)&K_lds[buf][(ni * 32 + lc5) * 40 + l5 * 8];
            ka[ni][1] = *(const short8*)&K_lds[buf][(ni * 32 + lc5) * 40 + 16 + l5 * 8];
        }

        __builtin_amdgcn_s_setprio(1);
        uint pa[4][4];
        #pragma unroll
        for (int ni = 0; ni < 2; ++ni) {
            union { f32x16 v; f32x4 q[4]; } cu;
            #pragma unroll
            for (int g = 0; g < 4; ++g)
                cu.q[g] = pch[(ni * 8 + 2 * g) * 256];
            f32x16 c = cu.v;
            c = __builtin_amdgcn_mfma_f32_32x32x16_bf16(ka[ni][0], qf[0], c, 0, 0, 0);
            c = __builtin_amdgcn_mfma_f32_32x32x16_bf16(ka[ni][1], qf[1], c, 0, 0, 0);
            // exp2 + truncate-pack to bf16 pairs (v_perm: 1 op per pair)
            uint u[4][2];
            #pragma unroll
            for (int g = 0; g < 4; ++g) {
                uint b0 = __builtin_bit_cast(uint, exp2f(c[4 * g]));
                uint b1 = __builtin_bit_cast(uint, exp2f(c[4 * g + 1]));
                uint b2 = __builtin_bit_cast(uint, exp2f(c[4 * g + 2]));
                uint b3 = __builtin_bit_cast(uint, exp2f(c[4 * g + 3]));
                u[g][0] = __builtin_amdgcn_perm(b1, b0, 0x07060302u);
                u[g][1] = __builtin_amdgcn_perm(b3, b2, 0x07060302u);
            }
            // lane^32 redistribution via permlane32_swap
            #pragma unroll
            for (int h = 0; h < 2; ++h) {
                uint w0 = u[2 * h][0], w1v = u[2 * h][1];
                uint w2v = u[2 * h + 1][0], w3 = u[2 * h + 1][1];
                asm("v_permlane32_swap_b32 %0, %1" : "+v"(w0), "+v"(w2v));
                asm("v_permlane32_swap_b32 %0, %1" : "+v"(w1v), "+v"(w3));
                pa[ni * 2 + h][0] = w0;
                pa[ni * 2 + h][1] = w1v;
                pa[ni * 2 + h][2] = w2v;
                pa[ni * 2 + h][3] = w3;
            }
        }
        // PV: 4 mfma
        #pragma unroll
        for (int ksl = 0; ksl < 4; ++ksl) {
            uint4v pw = {pa[ksl][0], pa[ksl][1], pa[ksl][2], pa[ksl][3]};
            oacc = __builtin_amdgcn_mfma_f32_32x32x16_bf16(
                __builtin_bit_cast(short8, pw), vb[ksl], oacc, 0, 0, 0);
        }
        __builtin_amdgcn_s_setprio(0);
        pch += 4096;   // 16 key-quads * 256

        if (ch < 8) {
            STORELDS(buf ^ 1);
            if (ch < 7) LOADKV();
        }
    }
    #undef LOADKV
    #undef STORELDS

    // ---- denominator = O[.][d=31] (lane l5*32+31); normalize + store
    #pragma unroll
    for (int r = 0; r < 16; ++r) {
        float invv = 1.f / oacc[r];
        float inv = __shfl(invv, (lane & 32) | 31);
        int row = (r & 3) + 8 * (r >> 2) + 4 * l5;
        int tok = w * 32 + row;
        int y = wi * 16 + (tok >> 4), x = wj * 16 + (tok & 15);
        long grow = (long)(b * 256 + y) * 256 + x;
        ushort val = (lc5 < 30) ? f2bf(oacc[r] * inv) : (ushort)0;
        obuf[grow * 192 + head * 32 + lc5] = val;
    }
}

// ---------------------------------------------------------------------------
extern "C" void kernel_launch(void* const* d_in, const int* in_sizes, int n_in,
                              void* d_out, int out_size, void* d_ws, size_t ws_size,
                              hipStream_t stream)
{
    const float* x      = (const float*)d_in[0];
    const int*   rpi    = (const int*)d_in[1];
    const float* qkv_w  = (const float*)d_in[2];
    const float* qkv_b  = (const float*)d_in[3];
    const float* proj_w = (const float*)d_in[4];
    const float* proj_b = (const float*)d_in[5];
    const float* rpb    = (const float*)d_in[6];
    const float* ln1_g  = (const float*)d_in[7];
    const float* ln1_b  = (const float*)d_in[8];
    const float* ln2_g  = (const float*)d_in[9];
    const float* ln2_b  = (const float*)d_in[10];
    const float* w1     = (const float*)d_in[11];
    const float* b1     = (const float*)d_in[12];
    const float* w2     = (const float*)d_in[13];
    const float* b2     = (const float*)d_in[14];
    float* out = (float*)d_out;
    char* ws = (char*)d_ws;

    ushort* wq_t     = (ushort*)(ws + 0);
    ushort* wp_t     = (ushort*)(ws + 221184);
    ushort* w1_t     = (ushort*)(ws + 294912);
    ushort* w2_t     = (ushort*)(ws + 442368);
    float*  bq       = (float*)(ws + 589824);
    float*  bp       = (float*)(ws + 592128);
    float*  b1p      = (float*)(ws + 592896);
    float*  b2p      = (float*)(ws + 594432);
    float*  bias_s   = (float*)(ws + 595200);      // 3538944 B
    ushort* hbuf     = (ushort*)(ws + 4194304);    // bf16 131072x192
    ushort* qkv      = (ushort*)(ws + 54525952);   // bf16 131072x576 (padded)
    ushort* x2b      = (ushort*)(ws + 54525952);   // bf16 131072x180, overlays qkv
    ushort* obuf     = (ushort*)(ws + 205520896);
    ushort* g1       = (ushort*)(ws + 205520896);  // overlays obuf

    prep_kernel<<<2022, 256, 0, stream>>>(qkv_w, qkv_b, proj_w, proj_b,
                                          w1, b1, w2, b2, rpi, rpb,
                                          wq_t, wp_t, w1_t, w2_t, bq, bp, b1p, b2p,
                                          bias_s);
    ln_kernel<0><<<32768, 256, 0, stream>>>(x, ln1_g, ln1_b, hbuf);
    gemm_kernel<192, 5, 0><<<dim3(5, 1024), 256, 0, stream>>>(hbuf, wq_t, bq, qkv, nullptr);
    attn_kernel<<<3072, 512, 0, stream>>>(qkv, bias_s, obuf);
    gemm_kernel<192, 2, 1><<<dim3(2, 1024), 256, 0, stream>>>(obuf, wp_t, bp, x2b, x);
    ln_kernel<1><<<32768, 256, 0, stream>>>(x2b, ln2_g, ln2_b, hbuf);
    gemm_kernel<192, 3, 2><<<dim3(3, 1024), 256, 0, stream>>>(hbuf, w1_t, b1p, g1, nullptr);
    gemm_kernel<384, 2, 3><<<dim3(2, 1024), 256, 0, stream>>>(g1, w2_t, b2p, out, x2b);
}

// Round 25
// 517.671 us; speedup vs baseline: 1.0193x; 1.0193x over previous
//
#include <hip/hip_runtime.h>
#include <hip/hip_bf16.h>
#include <math.h>

typedef unsigned int uint;
typedef unsigned short ushort;
typedef __attribute__((ext_vector_type(8))) short short8;
typedef __attribute__((ext_vector_type(4))) float f32x4;
typedef __attribute__((ext_vector_type(16))) float f32x16;
typedef __attribute__((ext_vector_type(4))) uint uint4v;

#define SCALE_Q 0.18257418583505536f   // 30^-0.5  (baked into Wq/bq)
#define LOG2E 1.4426950408889634f      // baked into Wk and bias_s

__device__ __forceinline__ ushort f2bf(float f) {
    union { float f; uint i; } v; v.f = f;
    uint i = v.i;
    uint r = (i + 0x7fffu + ((i >> 16) & 1u)) >> 16;
    return (ushort)r;
}
__device__ __forceinline__ float bf2f(ushort u) {
    union { uint i; float f; } v; v.i = ((uint)u) << 16; return v.f;
}

// ---------------------------------------------------------------------------
// prep + LN1 merged (isolated from R18's confounded experiment):
// blocks [0,32768) do LayerNorm1 (f32 x -> bf16 hbuf), blocks [32768,34790)
// do weight/bias prep. Both are independent streaming paths.
// ---------------------------------------------------------------------------
__global__ void prep_ln_kernel(const float* __restrict__ x, const float* __restrict__ ln1_g,
                               const float* __restrict__ ln1_b, ushort* __restrict__ hbuf,
                               const float* __restrict__ qkv_w, const float* __restrict__ qkv_b,
                               const float* __restrict__ proj_w, const float* __restrict__ proj_b,
                               const float* __restrict__ w1, const float* __restrict__ b1,
                               const float* __restrict__ w2, const float* __restrict__ b2,
                               const int* __restrict__ rpi, const float* __restrict__ rpb,
                               ushort* __restrict__ wq_t, ushort* __restrict__ wp_t,
                               ushort* __restrict__ w1_t, ushort* __restrict__ w2_t,
                               float* __restrict__ bq, float* __restrict__ bp,
                               float* __restrict__ b1p, float* __restrict__ b2p,
                               float* __restrict__ bias_s)
{
    if (blockIdx.x < 32768) {
        int row = blockIdx.x * 4 + (threadIdx.x >> 6);
        int lane = threadIdx.x & 63;
        const float* xr = x + (long)row * 180;
        float v0 = xr[lane];
        float v1 = xr[lane + 64];
        float v2 = (lane < 52) ? xr[lane + 128] : 0.f;
        float s = v0 + v1 + v2;
        float ss = v0 * v0 + v1 * v1 + v2 * v2;
        #pragma unroll
        for (int m = 1; m < 64; m <<= 1) { s += __shfl_xor(s, m); ss += __shfl_xor(ss, m); }
        float mu = s * (1.f / 180.f);
        float var = ss * (1.f / 180.f) - mu * mu;
        float rs = rsqrtf(var + 1e-5f);
        ushort* orow = hbuf + (long)row * 192;
        orow[lane]      = f2bf((v0 - mu) * rs * ln1_g[lane] + ln1_b[lane]);
        orow[lane + 64] = f2bf((v1 - mu) * rs * ln1_g[lane + 64] + ln1_b[lane + 64]);
        orow[lane + 128] = (lane < 52)
            ? f2bf((v2 - mu) * rs * ln1_g[lane + 128] + ln1_b[lane + 128])
            : (ushort)0;
        return;
    }
    int i = (blockIdx.x - 32768) * 256 + threadIdx.x;
    if (i < 576 * 192) { int n = i / 192, k = i % 192;
        float sc = (n < 180) ? SCALE_Q : ((n < 360) ? LOG2E : 1.f);
        wq_t[i] = (n < 540 && k < 180) ? f2bf(qkv_w[k * 540 + n] * sc) : (ushort)0; return; }
    i -= 576 * 192;
    if (i < 192 * 192) { int n = i / 192, k = i % 192;
        int h = k >> 5, d = k & 31;
        wp_t[i] = (n < 180 && d < 30) ? f2bf(proj_w[(h * 30 + d) * 180 + n]) : (ushort)0; return; }
    i -= 192 * 192;
    if (i < 384 * 192) { int n = i / 192, k = i % 192;
        w1_t[i] = (n < 360 && k < 180) ? f2bf(w1[k * 360 + n]) : (ushort)0; return; }
    i -= 384 * 192;
    if (i < 192 * 384) { int n = i / 384, k = i % 384;
        w2_t[i] = (n < 180 && k < 360) ? f2bf(w2[k * 180 + n]) : (ushort)0; return; }
    i -= 192 * 384;
    if (i < 576) {
        float sc = (i < 180) ? SCALE_Q : ((i < 360) ? LOG2E : 1.f);
        bq[i] = (i < 540) ? qkv_b[i] * sc : 0.f; return; }
    i -= 576;
    if (i < 192) { bp[i] = (i < 180) ? proj_b[i] : 0.f; return; }
    i -= 192;
    if (i < 384) { b1p[i] = (i < 360) ? b1[i] : 0.f; return; }
    i -= 384;
    if (i < 192) { b2p[i] = (i < 180) ? b2[i] : 0.f; return; }
    i -= 192;
    if (i < 221184) {   // bias part
        int h = i / 36864;
        int r = i % 36864;                         // kg*256 + q
        int kg = r >> 8, q = r & 255;
        const int* rp = rpi + q * 576 + kg * 4;
        f32x4 v;
        #pragma unroll
        for (int j = 0; j < 4; ++j) v[j] = rpb[rp[j] * 6 + h] * LOG2E;
        *(f32x4*)(bias_s + (long)i * 4) = v;
    }
}

// ---------------------------------------------------------------------------
// LayerNorm2: bf16 [rows][180] -> bf16 [rows][192]; pads ZEROED
// ---------------------------------------------------------------------------
__global__ void ln_kernel(const ushort* __restrict__ xin, const float* __restrict__ g,
                          const float* __restrict__ b, ushort* __restrict__ out)
{
    int row = blockIdx.x * 4 + (threadIdx.x >> 6);
    int lane = threadIdx.x & 63;
    const ushort* xr = xin + (long)row * 180;
    float v0 = bf2f(xr[lane]);
    float v1 = bf2f(xr[lane + 64]);
    float v2 = (lane < 52) ? bf2f(xr[lane + 128]) : 0.f;
    float s = v0 + v1 + v2;
    float ss = v0 * v0 + v1 * v1 + v2 * v2;
    #pragma unroll
    for (int m = 1; m < 64; m <<= 1) { s += __shfl_xor(s, m); ss += __shfl_xor(ss, m); }
    float mu = s * (1.f / 180.f);
    float var = ss * (1.f / 180.f) - mu * mu;
    float rs = rsqrtf(var + 1e-5f);
    ushort* orow = out + (long)row * 192;
    orow[lane]      = f2bf((v0 - mu) * rs * g[lane] + b[lane]);
    orow[lane + 64] = f2bf((v1 - mu) * rs * g[lane + 64] + b[lane + 64]);
    orow[lane + 128] = (lane < 52)
        ? f2bf((v2 - mu) * rs * g[lane + 128] + b[lane + 128])
        : (ushort)0;
}

// ---------------------------------------------------------------------------
// GEMM, 128x128 tile, 2-phase dbuf, one barrier per k-step.
// XCD-chunked block swizzle (T1). R22-verified, byte-identical.
// EPI 0: bf16 = acc+bias, padded qkv layout, col<576 (540..575 -> pad slots)
// EPI 1: bf16 = acc+bias+aux_f32, stride 180, col<180      (proj + residual)
// EPI 2: bf16 = gelu(acc+bias), stride 384                 (mlp1)
// EPI 3: f32  = acc+bias+aux_bf16, stride 180, col<180     (mlp2 + residual)
// ---------------------------------------------------------------------------
template<int KP, int NBX, int EPI>
__global__ __launch_bounds__(256)
void gemm_kernel(const ushort* __restrict__ A, const ushort* __restrict__ Bt,
                 const float* __restrict__ bias, void* __restrict__ outp,
                 const void* __restrict__ aux)
{
    __shared__ ushort As[2][128 * 32];
    __shared__ ushort Bs[2][128 * 32];
    constexpr int TOTAL = NBX * 1024;
    const int lin = blockIdx.y * NBX + blockIdx.x;
    const int lin2 = (lin & 7) * (TOTAL >> 3) + (lin >> 3);
    const int m0 = (lin2 / NBX) * 128;
    const int n0 = (lin2 % NBX) * 128;
    const int tid = threadIdx.x;
    const int lane = tid & 63;
    const int w = tid >> 6;
    const int wr = w >> 1, wc = w & 1;
    const int lg = lane >> 4, lc = lane & 15;

    f32x4 acc[4][4] = {};

    const int arow = tid >> 2;
    const int acol = (tid & 3) * 8;
    const ushort* gA = A + (long)(m0 + arow) * KP + acol;
    const ushort* gB = Bt + (long)(n0 + arow) * KP + acol;

    typedef const __attribute__((address_space(1))) char* gp_t;
    typedef __attribute__((address_space(3))) char* lp_t;

    const int kg = lg * 8;
    const int rA = wr * 64 + lc;
    const int rB = wc * 64 + lc;

    #define STAGE(buf, k0)                                                          \
        do {                                                                        \
            __builtin_amdgcn_global_load_lds((gp_t)(const char*)(gA + (k0)),        \
                (lp_t)(char*)(As[buf] + tid * 8), 16, 0, 0);                        \
            __builtin_amdgcn_global_load_lds((gp_t)(const char*)(gA + 64 * KP + (k0)),\
                (lp_t)(char*)(As[buf] + 2048 + tid * 8), 16, 0, 0);                 \
            __builtin_amdgcn_global_load_lds((gp_t)(const char*)(gB + (k0)),        \
                (lp_t)(char*)(Bs[buf] + tid * 8), 16, 0, 0);                        \
            __builtin_amdgcn_global_load_lds((gp_t)(const char*)(gB + 64 * KP + (k0)),\
                (lp_t)(char*)(Bs[buf] + 2048 + tid * 8), 16, 0, 0);                 \
        } while (0)

    STAGE(0, 0);
    __syncthreads();
    int cur = 0;
    for (int k0 = 0; k0 < KP; k0 += 32) {
        if (k0 + 32 < KP) STAGE(cur ^ 1, k0 + 32);
        short8 a[4], bb[4];
        #pragma unroll
        for (int mi = 0; mi < 4; ++mi)
            a[mi] = *(const short8*)&As[cur][(rA + mi * 16) * 32 + kg];
        #pragma unroll
        for (int ni = 0; ni < 4; ++ni)
            bb[ni] = *(const short8*)&Bs[cur][(rB + ni * 16) * 32 + kg];
        #pragma unroll
        for (int mi = 0; mi < 4; ++mi)
            #pragma unroll
            for (int ni = 0; ni < 4; ++ni)
                acc[mi][ni] = __builtin_amdgcn_mfma_f32_16x16x32_bf16(
                    a[mi], bb[ni], acc[mi][ni], 0, 0, 0);
        __syncthreads();
        cur ^= 1;
    }
    #undef STAGE

    #pragma unroll
    for (int mi = 0; mi < 4; ++mi) {
        #pragma unroll
        for (int ni = 0; ni < 4; ++ni) {
            int col = n0 + wc * 64 + ni * 16 + lc;
            int rbase = m0 + wr * 64 + mi * 16 + lg * 4;
            float bcol = bias[col];
            if (EPI == 0) {
                if (col < 576) {
                    int seg, hh, dd;
                    if (col < 540) {
                        seg = col / 180; int r2 = col - seg * 180;
                        hh = r2 / 30; dd = r2 - hh * 30;
                    } else {
                        int s2 = col - 540;
                        seg = s2 / 12; int r3 = s2 - seg * 12;
                        hh = r3 >> 1; dd = 30 + (r3 & 1);
                    }
                    int slot = seg * 192 + hh * 32 + dd;
                    #pragma unroll
                    for (int r = 0; r < 4; ++r) {
                        long row = rbase + r;
                        ((ushort*)outp)[row * 576 + slot] = f2bf(acc[mi][ni][r] + bcol);
                    }
                }
            } else if (EPI == 1) {
                if (col < 180) {
                    #pragma unroll
                    for (int r = 0; r < 4; ++r) {
                        long row = rbase + r;
                        ((ushort*)outp)[row * 180 + col] =
                            f2bf(acc[mi][ni][r] + bcol + ((const float*)aux)[row * 180 + col]);
                    }
                }
            } else if (EPI == 2) {
                #pragma unroll
                for (int r = 0; r < 4; ++r) {
                    long row = rbase + r;
                    float v = acc[mi][ni][r] + bcol;
                    float t = 0.5f * v * (1.f + erff(v * 0.70710678118654752f));
                    ((ushort*)outp)[row * 384 + col] = f2bf(t);
                }
            } else {
                if (col < 180) {
                    #pragma unroll
                    for (int r = 0; r < 4; ++r) {
                        long row = rbase + r;
                        ((float*)outp)[row * 180 + col] =
                            acc[mi][ni][r] + bcol
                            + bf2f(((const ushort*)aux)[row * 180 + col]);
                    }
                }
            }
        }
    }
}

// ---------------------------------------------------------------------------
// MFMA attention (R22-verified, byte-identical): 8 waves/block (512 threads),
// wave owns 32 q rows; K/V staged once (t<256 stages K, t>=256 stages V);
// 32x32 MFMA, in-register P, 1 barrier/chunk.
// ---------------------------------------------------------------------------
__global__ __launch_bounds__(512)
void attn_kernel(const ushort* __restrict__ qkv, const float* __restrict__ bias_s,
                 ushort* __restrict__ obuf)
{
    __shared__ ushort K_lds[2][64 * 40];
    __shared__ ushort Vt_lds[2][32 * 64];

    const int blk0 = blockIdx.x;
    const int blk = (blk0 & 7) * 384 + (blk0 >> 3);   // XCD-contiguous swizzle
    const int head = blk % 6;
    const int win = blk / 6;
    const int wj = win & 15, wi = (win >> 4) & 15, b = win >> 8;
    const int t = threadIdx.x;
    const int lane = t & 63;
    const int w = t >> 6;           // 0..7: wave owns q-tile w*32..w*32+31
    const int l5 = lane >> 5;       // 0..1
    const int lc5 = lane & 31;      // 0..31

    // Q fragment: B-operand, col(n)=q by lc5, k=d, two d-slices of 16
    short8 qf[2];
    {
        int tok = w * 32 + lc5;
        int y = wi * 16 + (tok >> 4), x = wj * 16 + (tok & 15);
        long grow = (long)(b * 256 + y) * 256 + x;
        #pragma unroll
        for (int ksl = 0; ksl < 2; ++ksl)
            qf[ksl] = *(const short8*)(qkv + grow * 576 + head * 32 + ksl * 16 + l5 * 8);
    }

    f32x16 oacc = {};
    const short8 zv = {0, 0, 0, 0, 0, 0, 0, 0};

    // staging split: t<256 stage K, t>=256 stage V (same keyloc/p4 mapping)
    const int isK = (t < 256);
    const int st = t & 255;
    const int keyloc = st >> 2;   // chunk-local key staged by this thread
    const int p4 = st & 3;        // 16B d-block

    const f32x4* pch = (const f32x4*)bias_s
                       + ((long)(head * 144 + l5) << 8) + (w * 32 + lc5);

    const ushort* kvbase = qkv + head * 32 + p4 * 8 + (isK ? 192 : 384);

    short8 kv;
    int kyS = keyloc / 24, kxS = keyloc - (keyloc / 24) * 24;

    #define LOADKV()                                                           \
        do {                                                                   \
            int gy = wi * 16 - 4 + kyS, gx = wj * 16 - 4 + kxS;                \
            bool ok = (gy >= 0 && gy < 256 && gx >= 0 && gx < 256);            \
            long grow = ok ? ((long)(b * 256 + gy) * 256 + gx) : 0;            \
            kv = *(const short8*)(kvbase + grow * 576);                        \
            if (!ok) kv = zv;                                                  \
            kxS += 16; kyS += 2;                                               \
            if (kxS >= 24) { kxS -= 24; kyS += 1; }                            \
        } while (0)

    #define STORELDS(buf)                                                      \
        do {                                                                   \
            if (isK) {                                                         \
                *(short8*)&K_lds[buf][keyloc * 40 + p4 * 8] = kv;              \
            } else {                                                           \
                _Pragma("unroll")                                              \
                for (int j = 0; j < 8; ++j) {                                  \
                    int d = p4 * 8 + j;                                        \
                    int swd = (((d & 7) ^ (d >> 3)) << 3);                     \
                    Vt_lds[buf][d * 64 + (keyloc ^ swd)] = ((const ushort*)&kv)[j];\
                }                                                              \
                if (p4 == 3) Vt_lds[buf][31 * 64 + (keyloc ^ 32)] = (ushort)0x3F80;\
            }                                                                  \
        } while (0)

    LOADKV();
    STORELDS(0);
    LOADKV();

    const int vswd = (((lc5 & 7) ^ (lc5 >> 3)) << 3);

    for (int ch = 0; ch < 9; ++ch) {
        __syncthreads();
        const int buf = ch & 1;

        // V B-fragments for the 4 k-slices
        short8 vb[4];
        #pragma unroll
        for (int ksl = 0; ksl < 4; ++ksl)
            vb[ksl] = *(const short8*)&Vt_lds[buf][lc5 * 64 + ((ksl * 16 + l5 * 8) ^ vswd)];

        // K A-fragments
        short8 ka[2][2];
        #pragma unroll
        for (int ni = 0; ni < 2; ++ni) {
            ka[ni][0] = *(const short8*)&K_lds[buf][(ni * 32 + lc5) * 40 + l5 * 8];
            ka[ni][1] = *(const short8*)&K_lds[buf][(ni * 32 + lc5) * 40 + 16 + l5 * 8];
        }

        __builtin_amdgcn_s_setprio(1);
        uint pa[4][4];
        #pragma unroll
        for (int ni = 0; ni < 2; ++ni) {
            union { f32x16 v; f32x4 q[4]; } cu;
            #pragma unroll
            for (int g = 0; g < 4; ++g)
                cu.q[g] = pch[(ni * 8 + 2 * g) * 256];
            f32x16 c = cu.v;
            c = __builtin_amdgcn_mfma_f32_32x32x16_bf16(ka[ni][0], qf[0], c, 0, 0, 0);
            c = __builtin_amdgcn_mfma_f32_32x32x16_bf16(ka[ni][1], qf[1], c, 0, 0, 0);
            // exp2 + truncate-pack to bf16 pairs (v_perm: 1 op per pair)
            uint u[4][2];
            #pragma unroll
            for (int g = 0; g < 4; ++g) {
                uint b0 = __builtin_bit_cast(uint, exp2f(c[4 * g]));
                uint b1 = __builtin_bit_cast(uint, exp2f(c[4 * g + 1]));
                uint b2 = __builtin_bit_cast(uint, exp2f(c[4 * g + 2]));
                uint b3 = __builtin_bit_cast(uint, exp2f(c[4 * g + 3]));
                u[g][0] = __builtin_amdgcn_perm(b1, b0, 0x07060302u);
                u[g][1] = __builtin_amdgcn_perm(b3, b2, 0x07060302u);
            }
            // lane^32 redistribution via permlane32_swap
            #pragma unroll
            for (int h = 0; h < 2; ++h) {
                uint w0 = u[2 * h][0], w1v = u[2 * h][1];
                uint w2v = u[2 * h + 1][0], w3 = u[2 * h + 1][1];
                asm("v_permlane32_swap_b32 %0, %1" : "+v"(w0), "+v"(w2v));
                asm("v_permlane32_swap_b32 %0, %1" : "+v"(w1v), "+v"(w3));
                pa[ni * 2 + h][0] = w0;
                pa[ni * 2 + h][1] = w1v;
                pa[ni * 2 + h][2] = w2v;
                pa[ni * 2 + h][3] = w3;
            }
        }
        // PV: 4 mfma
        #pragma unroll
        for (int ksl = 0; ksl < 4; ++ksl) {
            uint4v pw = {pa[ksl][0], pa[ksl][1], pa[ksl][2], pa[ksl][3]};
            oacc = __builtin_amdgcn_mfma_f32_32x32x16_bf16(
                __builtin_bit_cast(short8, pw), vb[ksl], oacc, 0, 0, 0);
        }
        __builtin_amdgcn_s_setprio(0);
        pch += 4096;   // 16 key-quads * 256

        if (ch < 8) {
            STORELDS(buf ^ 1);
            if (ch < 7) LOADKV();
        }
    }
    #undef LOADKV
    #undef STORELDS

    // ---- denominator = O[.][d=31] (lane l5*32+31); normalize + store
    #pragma unroll
    for (int r = 0; r < 16; ++r) {
        float invv = 1.f / oacc[r];
        float inv = __shfl(invv, (lane & 32) | 31);
        int row = (r & 3) + 8 * (r >> 2) + 4 * l5;
        int tok = w * 32 + row;
        int y = wi * 16 + (tok >> 4), x = wj * 16 + (tok & 15);
        long grow = (long)(b * 256 + y) * 256 + x;
        ushort val = (lc5 < 30) ? f2bf(oacc[r] * inv) : (ushort)0;
        obuf[grow * 192 + head * 32 + lc5] = val;
    }
}

// ---------------------------------------------------------------------------
extern "C" void kernel_launch(void* const* d_in, const int* in_sizes, int n_in,
                              void* d_out, int out_size, void* d_ws, size_t ws_size,
                              hipStream_t stream)
{
    const float* x      = (const float*)d_in[0];
    const int*   rpi    = (const int*)d_in[1];
    const float* qkv_w  = (const float*)d_in[2];
    const float* qkv_b  = (const float*)d_in[3];
    const float* proj_w = (const float*)d_in[4];
    const float* proj_b = (const float*)d_in[5];
    const float* rpb    = (const float*)d_in[6];
    const float* ln1_g  = (const float*)d_in[7];
    const float* ln1_b  = (const float*)d_in[8];
    const float* ln2_g  = (const float*)d_in[9];
    const float* ln2_b  = (const float*)d_in[10];
    const float* w1     = (const float*)d_in[11];
    const float* b1     = (const float*)d_in[12];
    const float* w2     = (const float*)d_in[13];
    const float* b2     = (const float*)d_in[14];
    float* out = (float*)d_out;
    char* ws = (char*)d_ws;

    ushort* wq_t     = (ushort*)(ws + 0);
    ushort* wp_t     = (ushort*)(ws + 221184);
    ushort* w1_t     = (ushort*)(ws + 294912);
    ushort* w2_t     = (ushort*)(ws + 442368);
    float*  bq       = (float*)(ws + 589824);
    float*  bp       = (float*)(ws + 592128);
    float*  b1p      = (float*)(ws + 592896);
    float*  b2p      = (float*)(ws + 594432);
    float*  bias_s   = (float*)(ws + 595200);      // 3538944 B
    ushort* hbuf     = (ushort*)(ws + 4194304);    // bf16 131072x192
    ushort* qkv      = (ushort*)(ws + 54525952);   // bf16 131072x576 (padded)
    ushort* x2b      = (ushort*)(ws + 54525952);   // bf16 131072x180, overlays qkv
    ushort* obuf     = (ushort*)(ws + 205520896);
    ushort* g1       = (ushort*)(ws + 205520896);  // overlays obuf

    prep_ln_kernel<<<34790, 256, 0, stream>>>(x, ln1_g, ln1_b, hbuf,
                                              qkv_w, qkv_b, proj_w, proj_b,
                                              w1, b1, w2, b2, rpi, rpb,
                                              wq_t, wp_t, w1_t, w2_t, bq, bp, b1p, b2p,
                                              bias_s);
    gemm_kernel<192, 5, 0><<<dim3(5, 1024), 256, 0, stream>>>(hbuf, wq_t, bq, qkv, nullptr);
    attn_kernel<<<3072, 512, 0, stream>>>(qkv, bias_s, obuf);
    gemm_kernel<192, 2, 1><<<dim3(2, 1024), 256, 0, stream>>>(obuf, wp_t, bp, x2b, x);
    ln_kernel<<<32768, 256, 0, stream>>>(x2b, ln2_g, ln2_b, hbuf);
    gemm_kernel<192, 3, 2><<<dim3(3, 1024), 256, 0, stream>>>(hbuf, w1_t, b1p, g1, nullptr);
    gemm_kernel<384, 2, 3><<<dim3(2, 1024), 256, 0, stream>>>(g1, w2_t, b2p, out, x2b);
}